// Round 3
// baseline (662.241 us; speedup 1.0000x reference)
//
#include <hip/hip_runtime.h>
#include <math.h>

#define BB 16
#define SS 256
#define DD 41
#define LL (SS*DD)      // 10496
#define LAT 128
#define NH 4
#define NL 3
#define KS 16           // key-split for MAB0
#define RSQ 0.08838834764831845f             // 1/sqrt(128)

typedef short bf16x8 __attribute__((ext_vector_type(8)));
typedef float f32x4 __attribute__((ext_vector_type(4)));
#define MFMA __builtin_amdgcn_mfma_f32_16x16x32_bf16

__device__ __forceinline__ unsigned short f2b(float f) {
    unsigned u = __builtin_bit_cast(unsigned, f);
    unsigned r = (u + 0x7FFFu + ((u >> 16) & 1u)) >> 16;
    return (unsigned short)r;
}
__device__ __forceinline__ float b2f(unsigned short h) {
    unsigned u = ((unsigned)h) << 16;
    return __builtin_bit_cast(float, u);
}

// ---------------- stable compaction (ballot/popcount scan) ----------------
__global__ __launch_bounds__(256)
void k_compact(const float* __restrict__ time_x, const float* __restrict__ value_x,
               const int* __restrict__ mask_x,
               float* __restrict__ compT, float* __restrict__ compU,
               int* __restrict__ compC, int* __restrict__ nvalid)
{
    int b = blockIdx.x, tid = threadIdx.x;
    int lane = tid & 63, w = tid >> 6;
    __shared__ int sW[4];
    __shared__ int s_base;
    if (tid == 0) s_base = 0;
    __syncthreads();
    for (int j0 = 0; j0 < LL; j0 += 256) {
        int j = j0 + tid;
        int m = mask_x[b * LL + j];
        unsigned long long bal = __ballot(m != 0);
        int pre = __popcll(bal & ((1ull << lane) - 1ull));
        if (lane == 0) sW[w] = __popcll(bal);
        __syncthreads();
        int woff = 0;
        for (int i = 0; i < w; ++i) woff += sW[i];
        int tot = sW[0] + sW[1] + sW[2] + sW[3];
        if (m) {
            int pos = s_base + woff + pre;
            compT[b * LL + pos] = time_x[b * SS + j / DD];
            compU[b * LL + pos] = value_x[b * LL + j];
            compC[b * LL + pos] = j % DD;
        }
        __syncthreads();
        if (tid == 0) s_base += tot;
        __syncthreads();
    }
    if (tid == 0) nvalid[b] = s_base;
}

// ---------------- Z init ----------------
__global__ __launch_bounds__(256)
void k_init(const float* __restrict__ Wi, const float* __restrict__ bi,
            const float* __restrict__ compT, const float* __restrict__ compU,
            const int* __restrict__ compC, const int* __restrict__ nvalid,
            float* __restrict__ out)
{
    int b = blockIdx.y, p0 = blockIdx.x * 8, tid = threadIdx.x;
    float* Z = out;
    float* MK = out + (size_t)BB * LL * LAT;
    int nv = nvalid[b];
    for (int s = 0; s < 4; ++s) {
        int e = s * 256 + tid;
        int r = e >> 7, k = e & 127;
        int p = p0 + r;
        size_t zi = ((size_t)b * LL + p) * LAT + k;
        if (p < nv) {
            int c = compC[b * LL + p];
            float t = compT[b * LL + p], u = compU[b * LL + p];
            float v = Wi[c * LAT + k] + t * Wi[41 * LAT + k] + u * Wi[42 * LAT + k] + bi[k];
            Z[zi] = fmaxf(v, 0.f);
        } else {
            Z[zi] = 0.f;
        }
        if (k == 0) MK[b * LL + p] = (p < nv) ? 1.f : 0.f;
    }
}

// ---------------- per-layer prep: Qh0 (f32+bf16), transposed bf16 weights ----------------
__global__ __launch_bounds__(256)
void k_prep(const float* __restrict__ Il, const float* __restrict__ Wq0,
            const float* __restrict__ bq0,
            const float* __restrict__ Wk0, const float* __restrict__ Wv0,
            const float* __restrict__ Wq1, const float* __restrict__ Wo1,
            float* __restrict__ Qh0f, unsigned short* __restrict__ Qh0b,
            unsigned short* __restrict__ WkT, unsigned short* __restrict__ WvT,
            unsigned short* __restrict__ WqT, unsigned short* __restrict__ WoT)
{
    __shared__ float srow[128];
    int blk = blockIdx.x, tid = threadIdx.x;
    if (blk < 128) {
        if (tid < 128) srow[tid] = Il[blk * 128 + tid];
        __syncthreads();
        if (tid < 128) {
            float acc = bq0[tid];
            for (int i = 0; i < 128; ++i) acc += srow[i] * Wq0[i * 128 + tid];
            Qh0f[blk * 128 + tid] = acc;
            Qh0b[blk * 128 + tid] = f2b(acc);
        }
    } else {
        const float* src = (blk == 128) ? Wk0 : (blk == 129) ? Wv0 : (blk == 130) ? Wq1 : Wo1;
        unsigned short* dst = (blk == 128) ? WkT : (blk == 129) ? WvT : (blk == 130) ? WqT : WoT;
        for (int e = tid; e < 16384; e += 256) {
            int i = e >> 7, n = e & 127;
            dst[n * 128 + i] = f2b(src[e]);
        }
    }
}

// ---------------- MAB0 flash (MFMA), dynamic key-split ----------------
__global__ __launch_bounds__(512)
void k_flash0(const float* __restrict__ Z, const unsigned short* __restrict__ Qh0b,
              const unsigned short* __restrict__ WkT, const unsigned short* __restrict__ WvT,
              const float* __restrict__ bk0, const float* __restrict__ bv0,
              const int* __restrict__ nvalid, float* __restrict__ ml,
              unsigned short* __restrict__ accp)
{
    const int chunk = blockIdx.x, b = blockIdx.y;
    const int tid = threadIdx.x, lane = tid & 63, w = tid >> 6;
    const int l16 = lane & 15, g4 = lane >> 4;
    const f32x4 fz = {0.f, 0.f, 0.f, 0.f};

    __shared__ unsigned short sZ[32 * 136];   // [kk][i]
    __shared__ unsigned short sKh[32 * 136];  // [kk][d]
    __shared__ unsigned short sVT[128 * 40];  // [d][kk]
    __shared__ float sS[128 * 33];            // [q][kk]
    __shared__ unsigned short sP[128 * 40];   // [q][kk]
    __shared__ float sM[NH * 128], sL[NH * 128], sScale[128];

    for (int e = tid; e < NH * 128; e += 512) { sM[e] = -1e30f; sL[e] = 0.f; }

    f32x4 acc[8];
    for (int n = 0; n < 8; ++n) acc[n] = fz;

    int nv = nvalid[b];
    int c0 = (int)(((long long)chunk * nv) / KS);
    int c1 = (int)(((long long)(chunk + 1) * nv) / KS);

    float bkd = bk0[w * 16 + l16];
    float bvd = bv0[w * 16 + l16];

    __syncthreads();

    for (int kt = c0; kt < c1; kt += 32) {
        int nk = min(32, c1 - kt);
        // stage Z tile f32->bf16
        {
            int r = tid >> 4, c = (tid & 15) * 8;
            bf16x8 v;
            if (r < nk) {
                const float* src = &Z[((size_t)b * LL + kt + r) * LAT + c];
                #pragma unroll
                for (int j = 0; j < 8; ++j) ((unsigned short*)&v)[j] = f2b(src[j]);
            } else {
                #pragma unroll
                for (int j = 0; j < 8; ++j) ((unsigned short*)&v)[j] = 0;
            }
            *(bf16x8*)&sZ[r * 136 + c] = v;
        }
        __syncthreads();
        // KV projection: wave w -> d-cols 16w..16w+15
        {
            f32x4 ck[2] = {fz, fz}, cv[2] = {fz, fz};
            #pragma unroll
            for (int k = 0; k < 4; ++k) {
                bf16x8 a0 = *(const bf16x8*)&sZ[(l16) * 136 + k * 32 + g4 * 8];
                bf16x8 a1 = *(const bf16x8*)&sZ[(16 + l16) * 136 + k * 32 + g4 * 8];
                bf16x8 bk_ = *(const bf16x8*)&WkT[(w * 16 + l16) * 128 + k * 32 + g4 * 8];
                bf16x8 bv_ = *(const bf16x8*)&WvT[(w * 16 + l16) * 128 + k * 32 + g4 * 8];
                ck[0] = MFMA(a0, bk_, ck[0], 0, 0, 0);
                ck[1] = MFMA(a1, bk_, ck[1], 0, 0, 0);
                cv[0] = MFMA(a0, bv_, cv[0], 0, 0, 0);
                cv[1] = MFMA(a1, bv_, cv[1], 0, 0, 0);
            }
            #pragma unroll
            for (int m = 0; m < 2; ++m)
                #pragma unroll
                for (int r = 0; r < 4; ++r) {
                    int kk = m * 16 + g4 * 4 + r;
                    int d = w * 16 + l16;
                    sKh[kk * 136 + d] = f2b(ck[m][r] + bkd);
                    sVT[d * 40 + kk] = f2b(cv[m][r] + bvd);
                }
        }
        __syncthreads();
        for (int h = 0; h < NH; ++h) {
            // scores: wave w owns q-rows 16w..16w+15
            bf16x8 aq = *(const bf16x8*)&Qh0b[(w * 16 + l16) * 128 + h * 32 + g4 * 8];
            #pragma unroll
            for (int n = 0; n < 2; ++n) {
                bf16x8 bk_ = *(const bf16x8*)&sKh[(n * 16 + l16) * 136 + h * 32 + g4 * 8];
                f32x4 s = MFMA(aq, bk_, fz, 0, 0, 0);
                #pragma unroll
                for (int r = 0; r < 4; ++r)
                    sS[(w * 16 + g4 * 4 + r) * 33 + n * 16 + l16] = s[r] * RSQ;
            }
            // wave-local online softmax: 4 lanes per row
            int q = w * 16 + (lane >> 2);
            int k0 = (lane & 3) * 8;
            float sv[8];
            float mx = -1e30f;
            #pragma unroll
            for (int j = 0; j < 8; ++j) {
                int kk = k0 + j;
                sv[j] = (kk < nk) ? sS[q * 33 + kk] : -1e30f;
                mx = fmaxf(mx, sv[j]);
            }
            mx = fmaxf(mx, __shfl_xor(mx, 1));
            mx = fmaxf(mx, __shfl_xor(mx, 2));
            float mr = sM[h * 128 + q];
            float mn = fmaxf(mr, mx);
            float sc = __expf(mr - mn);
            float ls = 0.f;
            bf16x8 pv;
            #pragma unroll
            for (int j = 0; j < 8; ++j) {
                float p = (k0 + j < nk) ? __expf(sv[j] - mn) : 0.f;
                ((unsigned short*)&pv)[j] = f2b(p);
                ls += p;
            }
            *(bf16x8*)&sP[q * 40 + k0] = pv;
            ls += __shfl_xor(ls, 1);
            ls += __shfl_xor(ls, 2);
            if ((lane & 3) == 0) {
                sM[h * 128 + q] = mn;
                sL[h * 128 + q] = sL[h * 128 + q] * sc + ls;
                sScale[q] = sc;
            }
            // rescale this head's acc tiles, then PV
            #pragma unroll
            for (int nn = 0; nn < 2; ++nn) {
                int nt = 2 * h + nn;
                #pragma unroll
                for (int r = 0; r < 4; ++r) {
                    float scq = sScale[w * 16 + g4 * 4 + r];
                    acc[nt][r] *= scq;
                }
            }
            bf16x8 aP = *(const bf16x8*)&sP[(w * 16 + l16) * 40 + g4 * 8];
            #pragma unroll
            for (int nn = 0; nn < 2; ++nn) {
                bf16x8 bV = *(const bf16x8*)&sVT[(h * 32 + nn * 16 + l16) * 40 + g4 * 8];
                acc[2 * h + nn] = MFMA(aP, bV, acc[2 * h + nn], 0, 0, 0);
            }
        }
        __syncthreads();
    }
    __syncthreads();
    size_t mlbase = (((size_t)b * KS + chunk) * NH) * 128 * 2;
    for (int e = tid; e < NH * 128; e += 512) {
        ml[mlbase + e * 2 + 0] = sM[e];
        ml[mlbase + e * 2 + 1] = sL[e];
    }
    size_t abase = (((size_t)b * KS + chunk) * 128) * 128;
    #pragma unroll
    for (int n = 0; n < 8; ++n)
        #pragma unroll
        for (int r = 0; r < 4; ++r) {
            int q = w * 16 + g4 * 4 + r;
            int d = n * 16 + l16;
            accp[abase + (size_t)q * 128 + d] = f2b(acc[n][r]);
        }
}

// ---------------- fused: merge MAB0 partials -> O0 -> H -> Kh1b/Vh1Tb ----------------
__global__ __launch_bounds__(128)
void k_post0(const float* __restrict__ ml, const unsigned short* __restrict__ accp,
             const float* __restrict__ Qh0f,
             const float* __restrict__ Wo0, const float* __restrict__ bo0,
             const float* __restrict__ Wk1, const float* __restrict__ bk1,
             const float* __restrict__ Wv1, const float* __restrict__ bv1,
             unsigned short* __restrict__ Kh1b, unsigned short* __restrict__ Vh1Tb)
{
    int q = blockIdx.x, b = blockIdx.y, d = threadIdx.x, h = d >> 5;
    __shared__ float sx[128], sh2[128];
    float M = -1e30f;
    for (int c = 0; c < KS; ++c)
        M = fmaxf(M, ml[((((size_t)b * KS + c) * NH + h) * 128 + q) * 2]);
    float L = 0.f, A = 0.f;
    for (int c = 0; c < KS; ++c) {
        size_t base = ((((size_t)b * KS + c) * NH + h) * 128 + q) * 2;
        float sc = __expf(ml[base] - M);
        L += sc * ml[base + 1];
        A += sc * b2f(accp[(((size_t)b * KS + c) * 128 + q) * 128 + d]);
    }
    float o0 = Qh0f[q * 128 + d] + ((L > 0.f) ? A / L : 0.f);
    sx[d] = o0;
    __syncthreads();
    float acc = bo0[d];
    for (int i = 0; i < 128; ++i) acc += sx[i] * Wo0[i * 128 + d];
    float hv = o0 + fmaxf(acc, 0.f);
    sh2[d] = hv;
    __syncthreads();
    float ak = bk1[d], av = bv1[d];
    for (int i = 0; i < 128; ++i) {
        float x = sh2[i];
        ak += x * Wk1[i * 128 + d];
        av += x * Wv1[i * 128 + d];
    }
    Kh1b[((size_t)b * 128 + q) * 128 + d] = f2b(ak);
    Vh1Tb[((size_t)b * 128 + d) * 128 + q] = f2b(av);
}

// ---------------- MAB1 fused (MFMA, in-register softmax), 64 rows/block ----------------
__global__ __launch_bounds__(512, 4)
void k_mab1(float* __restrict__ Z, const unsigned short* __restrict__ Kh1b,
            const unsigned short* __restrict__ Vh1Tb,
            const unsigned short* __restrict__ WqT, const float* __restrict__ bq1,
            const unsigned short* __restrict__ WoT, const float* __restrict__ bo1,
            const int* __restrict__ nvalid)
{
    const int b = blockIdx.y;
    const int p0 = blockIdx.x * 64;
    const int nv = nvalid[b];
    if (p0 >= nv) return;
    const int tid = threadIdx.x, lane = tid & 63, w = tid >> 6;
    const int l16 = lane & 15, g4 = lane >> 4;
    const f32x4 fz = {0.f, 0.f, 0.f, 0.f};

    __shared__ unsigned short sQh[64 * 136];      // Qh1 [q][d]
    __shared__ unsigned short sPw[8][16 * 136];   // per-wave P scratch [qlocal][key]
    __shared__ unsigned short sO[64 * 136];       // O = Qh + attn

    // ---- Qh1 = Z @ Wq1 + bq1 ; wave w -> col-tile w; A-frags straight from global Z
    {
        f32x4 c4[4] = {fz, fz, fz, fz};
        #pragma unroll
        for (int ks = 0; ks < 4; ++ks) {
            bf16x8 bw = *(const bf16x8*)&WqT[(w * 16 + l16) * 128 + ks * 32 + g4 * 8];
            #pragma unroll
            for (int mt = 0; mt < 4; ++mt) {
                const float* zr = &Z[((size_t)b * LL + p0 + mt * 16 + l16) * LAT + ks * 32 + g4 * 8];
                bf16x8 a;
                #pragma unroll
                for (int j = 0; j < 8; ++j) ((unsigned short*)&a)[j] = f2b(zr[j]);
                c4[mt] = MFMA(a, bw, c4[mt], 0, 0, 0);
            }
        }
        float bqv = bq1[w * 16 + l16];
        #pragma unroll
        for (int mt = 0; mt < 4; ++mt)
            #pragma unroll
            for (int r = 0; r < 4; ++r)
                sQh[(mt * 16 + g4 * 4 + r) * 136 + w * 16 + l16] = f2b(c4[mt][r] + bqv);
    }
    __syncthreads();

    const int t = w >> 1;             // q-tile (16 rows)
    const int hbase = (w & 1) * 2;    // this wave's heads: hbase, hbase+1
    unsigned short* ps = sPw[w];
    f32x4 oacc[2][2];                 // [hh][nn]

    #pragma unroll
    for (int hh = 0; hh < 2; ++hh) {
        const int h = hbase + hh;
        // swapped scores: lane holds S[key=mt*16+4*g4+r][q=t*16+l16]
        f32x4 s[8];
        bf16x8 bq8 = *(const bf16x8*)&sQh[(t * 16 + l16) * 136 + h * 32 + g4 * 8];
        #pragma unroll
        for (int mt = 0; mt < 8; ++mt) {
            bf16x8 ak = *(const bf16x8*)&Kh1b[((size_t)b * 128 + mt * 16 + l16) * 128 + h * 32 + g4 * 8];
            s[mt] = MFMA(ak, bq8, fz, 0, 0, 0);
        }
        // in-register softmax over all 128 keys for q = t*16+l16
        float mx = -1e30f;
        #pragma unroll
        for (int mt = 0; mt < 8; ++mt)
            #pragma unroll
            for (int r = 0; r < 4; ++r) mx = fmaxf(mx, s[mt][r]);
        mx = fmaxf(mx, __shfl_xor(mx, 16));
        mx = fmaxf(mx, __shfl_xor(mx, 32));
        float ls = 0.f;
        #pragma unroll
        for (int mt = 0; mt < 8; ++mt)
            #pragma unroll
            for (int r = 0; r < 4; ++r) {
                float p = __expf((s[mt][r] - mx) * RSQ);
                s[mt][r] = p;
                ls += p;
            }
        ls += __shfl_xor(ls, 16);
        ls += __shfl_xor(ls, 32);
        float inv = 1.f / ls;
        // write scaled P to per-wave scratch: [qlocal=l16][key], 4 keys per b64 write
        #pragma unroll
        for (int mt = 0; mt < 8; ++mt) {
            unsigned short p4[4];
            #pragma unroll
            for (int r = 0; r < 4; ++r) p4[r] = f2b(s[mt][r] * inv);
            *(uint2*)&ps[l16 * 136 + mt * 16 + g4 * 4] = *(const uint2*)p4;
        }
        // PV: A = P rows from scratch, B = V^T rows from global
        #pragma unroll
        for (int nn = 0; nn < 2; ++nn) {
            f32x4 o = fz;
            #pragma unroll
            for (int ks = 0; ks < 4; ++ks) {
                bf16x8 aP = *(const bf16x8*)&ps[l16 * 136 + ks * 32 + g4 * 8];
                bf16x8 bV = *(const bf16x8*)&Vh1Tb[((size_t)b * 128 + h * 32 + nn * 16 + l16) * 128 + ks * 32 + g4 * 8];
                o = MFMA(aP, bV, o, 0, 0, 0);
            }
            oacc[hh][nn] = o;
        }
    }
    // O = Qh + attn -> sO
    #pragma unroll
    for (int hh = 0; hh < 2; ++hh)
        #pragma unroll
        for (int nn = 0; nn < 2; ++nn) {
            int col = (hbase + hh) * 32 + nn * 16 + l16;
            #pragma unroll
            for (int r = 0; r < 4; ++r) {
                int row = t * 16 + g4 * 4 + r;
                float val = oacc[hh][nn][r] + b2f(sQh[row * 136 + col]);
                sO[row * 136 + col] = f2b(val);
            }
        }
    __syncthreads();
    // out = Zold + O + relu(O @ Wo1 + bo1); wave w -> col-tile w
    {
        f32x4 c4[4] = {fz, fz, fz, fz};
        #pragma unroll
        for (int ks = 0; ks < 4; ++ks) {
            bf16x8 bw = *(const bf16x8*)&WoT[(w * 16 + l16) * 128 + ks * 32 + g4 * 8];
            #pragma unroll
            for (int mt = 0; mt < 4; ++mt) {
                bf16x8 a = *(const bf16x8*)&sO[(mt * 16 + l16) * 136 + ks * 32 + g4 * 8];
                c4[mt] = MFMA(a, bw, c4[mt], 0, 0, 0);
            }
        }
        float bov = bo1[w * 16 + l16];
        #pragma unroll
        for (int mt = 0; mt < 4; ++mt)
            #pragma unroll
            for (int r = 0; r < 4; ++r) {
                int row = mt * 16 + g4 * 4 + r;
                int col = w * 16 + l16;
                if (p0 + row < nv) {
                    size_t zi = ((size_t)b * LL + p0 + row) * LAT + col;
                    Z[zi] = Z[zi] + b2f(sO[row * 136 + col]) + fmaxf(c4[mt][r] + bov, 0.f);
                }
            }
    }
}

extern "C" void kernel_launch(void* const* d_in, const int* in_sizes, int n_in,
                              void* d_out, int out_size, void* d_ws, size_t ws_size,
                              hipStream_t stream)
{
    const float* time_x  = (const float*)d_in[0];
    const float* value_x = (const float*)d_in[1];
    const int*   mask_x  = (const int*)d_in[2];
    const float* Wi = (const float*)d_in[3];
    const float* bi = (const float*)d_in[4];
    const float* I  = (const float*)d_in[5];
    const float* Wq = (const float*)d_in[6];
    const float* bq = (const float*)d_in[7];
    const float* Wk = (const float*)d_in[8];
    const float* bk = (const float*)d_in[9];
    const float* Wv = (const float*)d_in[10];
    const float* bv = (const float*)d_in[11];
    const float* Wo = (const float*)d_in[12];
    const float* bo = (const float*)d_in[13];
    float* out = (float*)d_out;

    const size_t BL = (size_t)BB * LL;
    float* ws = (float*)d_ws;
    float* compT  = ws;                      ws += BL;
    float* compU  = ws;                      ws += BL;
    int*   compC  = (int*)ws;                ws += BL;
    int*   nvalid = (int*)ws;                ws += 64;
    float* Qh0f   = ws;                      ws += 16384;
    float* ml     = ws;                      ws += (size_t)BB * KS * NH * 128 * 2;
    unsigned short* accp  = (unsigned short*)ws;  ws += ((size_t)BB * KS * 128 * 128) / 2;
    unsigned short* Qh0b  = (unsigned short*)ws;  ws += 8192;
    unsigned short* WkT   = (unsigned short*)ws;  ws += 8192;
    unsigned short* WvT   = (unsigned short*)ws;  ws += 8192;
    unsigned short* WqT   = (unsigned short*)ws;  ws += 8192;
    unsigned short* WoT   = (unsigned short*)ws;  ws += 8192;
    unsigned short* Kh1b  = (unsigned short*)ws;  ws += ((size_t)BB * 16384) / 2;
    unsigned short* Vh1Tb = (unsigned short*)ws;  ws += ((size_t)BB * 16384) / 2;

    k_compact<<<BB, 256, 0, stream>>>(time_x, value_x, mask_x, compT, compU, compC, nvalid);
    k_init<<<dim3(LL / 8, BB), 256, 0, stream>>>(Wi, bi, compT, compU, compC, nvalid, out);

    for (int l = 0; l < NL; ++l) {
        const float* Wq0 = Wq + (size_t)(l * 2 + 0) * 16384;
        const float* Wk0 = Wk + (size_t)(l * 2 + 0) * 16384;
        const float* Wv0 = Wv + (size_t)(l * 2 + 0) * 16384;
        const float* Wo0 = Wo + (size_t)(l * 2 + 0) * 16384;
        const float* Wq1 = Wq + (size_t)(l * 2 + 1) * 16384;
        const float* Wk1 = Wk + (size_t)(l * 2 + 1) * 16384;
        const float* Wv1 = Wv + (size_t)(l * 2 + 1) * 16384;
        const float* Wo1 = Wo + (size_t)(l * 2 + 1) * 16384;
        const float* bq0 = bq + (l * 2 + 0) * 128;
        const float* bk0 = bk + (l * 2 + 0) * 128;
        const float* bv0 = bv + (l * 2 + 0) * 128;
        const float* bo0 = bo + (l * 2 + 0) * 128;
        const float* bq1 = bq + (l * 2 + 1) * 128;
        const float* bk1 = bk + (l * 2 + 1) * 128;
        const float* bv1 = bv + (l * 2 + 1) * 128;
        const float* bo1 = bo + (l * 2 + 1) * 128;
        const float* Il  = I + (size_t)l * 16384;

        k_prep<<<132, 256, 0, stream>>>(Il, Wq0, bq0, Wk0, Wv0, Wq1, Wo1,
                                        Qh0f, Qh0b, WkT, WvT, WqT, WoT);
        k_flash0<<<dim3(KS, BB), 512, 0, stream>>>(out, Qh0b, WkT, WvT, bk0, bv0,
                                                   nvalid, ml, accp);
        k_post0<<<dim3(128, BB), 128, 0, stream>>>(ml, accp, Qh0f, Wo0, bo0,
                                                   Wk1, bk1, Wv1, bv1, Kh1b, Vh1Tb);
        k_mab1<<<dim3(LL / 64, BB), 512, 0, stream>>>(out, Kh1b, Vh1Tb,
                                                      WqT, bq1, WoT, bo1, nvalid);
    }
}

// Round 4
// 573.112 us; speedup vs baseline: 1.1555x; 1.1555x over previous
//
#include <hip/hip_runtime.h>
#include <math.h>

#define BB 16
#define SS 256
#define DD 41
#define LL (SS*DD)      // 10496
#define LAT 128
#define NH 4
#define NL 3
#define KS 16           // key-split for MAB0
#define RSQ 0.08838834764831845f             // 1/sqrt(128)

typedef short bf16x8 __attribute__((ext_vector_type(8)));
typedef float f32x4 __attribute__((ext_vector_type(4)));
#define MFMA __builtin_amdgcn_mfma_f32_16x16x32_bf16

__device__ __forceinline__ unsigned short f2b(float f) {
    unsigned u = __builtin_bit_cast(unsigned, f);
    unsigned r = (u + 0x7FFFu + ((u >> 16) & 1u)) >> 16;
    return (unsigned short)r;
}
__device__ __forceinline__ float b2f(unsigned short h) {
    unsigned u = ((unsigned)h) << 16;
    return __builtin_bit_cast(float, u);
}

// ---------------- stable compaction (ballot/popcount scan) ----------------
__global__ __launch_bounds__(256)
void k_compact(const float* __restrict__ time_x, const float* __restrict__ value_x,
               const int* __restrict__ mask_x,
               float* __restrict__ compT, float* __restrict__ compU,
               int* __restrict__ compC, int* __restrict__ nvalid)
{
    int b = blockIdx.x, tid = threadIdx.x;
    int lane = tid & 63, w = tid >> 6;
    __shared__ int sW[4];
    __shared__ int s_base;
    if (tid == 0) s_base = 0;
    __syncthreads();
    for (int j0 = 0; j0 < LL; j0 += 256) {
        int j = j0 + tid;
        int m = mask_x[b * LL + j];
        unsigned long long bal = __ballot(m != 0);
        int pre = __popcll(bal & ((1ull << lane) - 1ull));
        if (lane == 0) sW[w] = __popcll(bal);
        __syncthreads();
        int woff = 0;
        for (int i = 0; i < w; ++i) woff += sW[i];
        int tot = sW[0] + sW[1] + sW[2] + sW[3];
        if (m) {
            int pos = s_base + woff + pre;
            compT[b * LL + pos] = time_x[b * SS + j / DD];
            compU[b * LL + pos] = value_x[b * LL + j];
            compC[b * LL + pos] = j % DD;
        }
        __syncthreads();
        if (tid == 0) s_base += tot;
        __syncthreads();
    }
    if (tid == 0) nvalid[b] = s_base;
}

// ---------------- Z init ----------------
__global__ __launch_bounds__(256)
void k_init(const float* __restrict__ Wi, const float* __restrict__ bi,
            const float* __restrict__ compT, const float* __restrict__ compU,
            const int* __restrict__ compC, const int* __restrict__ nvalid,
            float* __restrict__ out)
{
    int b = blockIdx.y, p0 = blockIdx.x * 8, tid = threadIdx.x;
    float* Z = out;
    float* MK = out + (size_t)BB * LL * LAT;
    int nv = nvalid[b];
    for (int s = 0; s < 4; ++s) {
        int e = s * 256 + tid;
        int r = e >> 7, k = e & 127;
        int p = p0 + r;
        size_t zi = ((size_t)b * LL + p) * LAT + k;
        if (p < nv) {
            int c = compC[b * LL + p];
            float t = compT[b * LL + p], u = compU[b * LL + p];
            float v = Wi[c * LAT + k] + t * Wi[41 * LAT + k] + u * Wi[42 * LAT + k] + bi[k];
            Z[zi] = fmaxf(v, 0.f);
        } else {
            Z[zi] = 0.f;
        }
        if (k == 0) MK[b * LL + p] = (p < nv) ? 1.f : 0.f;
    }
}

// ---------------- prep (all layers): Qh0 (f32+bf16), transposed bf16 weights ----------------
__global__ __launch_bounds__(256)
void k_prep(const float* __restrict__ I, const float* __restrict__ Wq,
            const float* __restrict__ bq,
            const float* __restrict__ Wk, const float* __restrict__ Wv,
            const float* __restrict__ Wo,
            float* __restrict__ Qh0f, unsigned short* __restrict__ Qh0b,
            unsigned short* __restrict__ WkT, unsigned short* __restrict__ WvT,
            unsigned short* __restrict__ WqT, unsigned short* __restrict__ WoT)
{
    __shared__ float srow[128];
    int blk = blockIdx.x, tid = threadIdx.x, l = blockIdx.y;
    const float* Il  = I  + (size_t)l * 16384;
    const float* Wq0 = Wq + (size_t)(l * 2 + 0) * 16384;
    const float* bq0 = bq + (size_t)(l * 2 + 0) * 128;
    const float* Wk0 = Wk + (size_t)(l * 2 + 0) * 16384;
    const float* Wv0 = Wv + (size_t)(l * 2 + 0) * 16384;
    const float* Wq1 = Wq + (size_t)(l * 2 + 1) * 16384;
    const float* Wo1 = Wo + (size_t)(l * 2 + 1) * 16384;
    if (blk < 128) {
        if (tid < 128) srow[tid] = Il[blk * 128 + tid];
        __syncthreads();
        if (tid < 128) {
            float acc = bq0[tid];
            for (int i = 0; i < 128; ++i) acc += srow[i] * Wq0[i * 128 + tid];
            Qh0f[(size_t)l * 16384 + blk * 128 + tid] = acc;
            Qh0b[(size_t)l * 16384 + blk * 128 + tid] = f2b(acc);
        }
    } else {
        const float* src = (blk == 128) ? Wk0 : (blk == 129) ? Wv0 : (blk == 130) ? Wq1 : Wo1;
        unsigned short* dst = (blk == 128) ? WkT : (blk == 129) ? WvT : (blk == 130) ? WqT : WoT;
        dst += (size_t)l * 16384;
        for (int e = tid; e < 16384; e += 256) {
            int i = e >> 7, n = e & 127;
            dst[n * 128 + i] = f2b(src[e]);
        }
    }
}

// ---------------- MAB0 flash (MFMA), dynamic key-split, reg-prefetched staging ----------------
__global__ __launch_bounds__(512, 4)
void k_flash0(const float* __restrict__ Z, const unsigned short* __restrict__ Qh0b,
              const unsigned short* __restrict__ WkT, const unsigned short* __restrict__ WvT,
              const float* __restrict__ bk0, const float* __restrict__ bv0,
              const int* __restrict__ nvalid, float* __restrict__ ml,
              unsigned short* __restrict__ accp)
{
    const int chunk = blockIdx.x, b = blockIdx.y;
    const int tid = threadIdx.x, lane = tid & 63, w = tid >> 6;
    const int l16 = lane & 15, g4 = lane >> 4;
    const f32x4 fz = {0.f, 0.f, 0.f, 0.f};

    __shared__ unsigned short sZ[32 * 136];   // [kk][i]
    __shared__ unsigned short sKh[32 * 136];  // [kk][d]
    __shared__ unsigned short sVT[128 * 40];  // [d][kk]
    __shared__ float sS[128 * 33];            // [q][kk]
    __shared__ unsigned short sP[128 * 40];   // [q][kk]
    __shared__ float sM[NH * 128], sL[NH * 128], sScale[128];

    for (int e = tid; e < NH * 128; e += 512) { sM[e] = -1e30f; sL[e] = 0.f; }

    f32x4 acc[8];
    for (int n = 0; n < 8; ++n) acc[n] = fz;

    int nv = nvalid[b];
    int c0 = (int)(((long long)chunk * nv) / KS);
    int c1 = (int)(((long long)(chunk + 1) * nv) / KS);

    float bkd = bk0[w * 16 + l16];
    float bvd = bv0[w * 16 + l16];

    const int sr = tid >> 4, sc = (tid & 15) * 8;   // staging coords
    float4 pa, pb;
    if (c0 < c1) {
        const float* s = &Z[((size_t)b * LL + c0 + sr) * LAT + sc];
        pa = *(const float4*)s; pb = *(const float4*)(s + 4);
    }

    __syncthreads();

    for (int kt = c0; kt < c1; kt += 32) {
        int nk = min(32, c1 - kt);
        // write staged tile (f32 regs -> bf16 LDS); rows >= nk zeroed
        {
            bf16x8 v;
            if (sr < nk) {
                ((unsigned short*)&v)[0] = f2b(pa.x);
                ((unsigned short*)&v)[1] = f2b(pa.y);
                ((unsigned short*)&v)[2] = f2b(pa.z);
                ((unsigned short*)&v)[3] = f2b(pa.w);
                ((unsigned short*)&v)[4] = f2b(pb.x);
                ((unsigned short*)&v)[5] = f2b(pb.y);
                ((unsigned short*)&v)[6] = f2b(pb.z);
                ((unsigned short*)&v)[7] = f2b(pb.w);
            } else {
                #pragma unroll
                for (int j = 0; j < 8; ++j) ((unsigned short*)&v)[j] = 0;
            }
            *(bf16x8*)&sZ[sr * 136 + sc] = v;
        }
        __syncthreads();
        // prefetch next tile (hides under proj + heads; drained at next barrier)
        if (kt + 32 < c1) {
            const float* s = &Z[((size_t)b * LL + kt + 32 + sr) * LAT + sc];
            pa = *(const float4*)s; pb = *(const float4*)(s + 4);
        }
        // KV projection: wave w -> d-cols 16w..16w+15
        {
            f32x4 ck[2] = {fz, fz}, cv[2] = {fz, fz};
            #pragma unroll
            for (int k = 0; k < 4; ++k) {
                bf16x8 a0 = *(const bf16x8*)&sZ[(l16) * 136 + k * 32 + g4 * 8];
                bf16x8 a1 = *(const bf16x8*)&sZ[(16 + l16) * 136 + k * 32 + g4 * 8];
                bf16x8 bk_ = *(const bf16x8*)&WkT[(w * 16 + l16) * 128 + k * 32 + g4 * 8];
                bf16x8 bv_ = *(const bf16x8*)&WvT[(w * 16 + l16) * 128 + k * 32 + g4 * 8];
                ck[0] = MFMA(a0, bk_, ck[0], 0, 0, 0);
                ck[1] = MFMA(a1, bk_, ck[1], 0, 0, 0);
                cv[0] = MFMA(a0, bv_, cv[0], 0, 0, 0);
                cv[1] = MFMA(a1, bv_, cv[1], 0, 0, 0);
            }
            #pragma unroll
            for (int m = 0; m < 2; ++m)
                #pragma unroll
                for (int r = 0; r < 4; ++r) {
                    int kk = m * 16 + g4 * 4 + r;
                    int d = w * 16 + l16;
                    sKh[kk * 136 + d] = f2b(ck[m][r] + bkd);
                    sVT[d * 40 + kk] = f2b(cv[m][r] + bvd);
                }
        }
        __syncthreads();
        for (int h = 0; h < NH; ++h) {
            // scores: wave w owns q-rows 16w..16w+15
            bf16x8 aq = *(const bf16x8*)&Qh0b[(w * 16 + l16) * 128 + h * 32 + g4 * 8];
            #pragma unroll
            for (int n = 0; n < 2; ++n) {
                bf16x8 bk_ = *(const bf16x8*)&sKh[(n * 16 + l16) * 136 + h * 32 + g4 * 8];
                f32x4 s = MFMA(aq, bk_, fz, 0, 0, 0);
                #pragma unroll
                for (int r = 0; r < 4; ++r)
                    sS[(w * 16 + g4 * 4 + r) * 33 + n * 16 + l16] = s[r] * RSQ;
            }
            // wave-local online softmax: 4 lanes per row
            int q = w * 16 + (lane >> 2);
            int k0 = (lane & 3) * 8;
            float sv[8];
            float mx = -1e30f;
            #pragma unroll
            for (int j = 0; j < 8; ++j) {
                int kk = k0 + j;
                sv[j] = (kk < nk) ? sS[q * 33 + kk] : -1e30f;
                mx = fmaxf(mx, sv[j]);
            }
            mx = fmaxf(mx, __shfl_xor(mx, 1));
            mx = fmaxf(mx, __shfl_xor(mx, 2));
            float mr = sM[h * 128 + q];
            float mn = fmaxf(mr, mx);
            float sc = __expf(mr - mn);
            float ls = 0.f;
            bf16x8 pv;
            #pragma unroll
            for (int j = 0; j < 8; ++j) {
                float p = (k0 + j < nk) ? __expf(sv[j] - mn) : 0.f;
                ((unsigned short*)&pv)[j] = f2b(p);
                ls += p;
            }
            *(bf16x8*)&sP[q * 40 + k0] = pv;
            ls += __shfl_xor(ls, 1);
            ls += __shfl_xor(ls, 2);
            if ((lane & 3) == 0) {
                sM[h * 128 + q] = mn;
                sL[h * 128 + q] = sL[h * 128 + q] * sc + ls;
                sScale[q] = sc;
            }
            // rescale this head's acc tiles, then PV
            #pragma unroll
            for (int nn = 0; nn < 2; ++nn) {
                int nt = 2 * h + nn;
                #pragma unroll
                for (int r = 0; r < 4; ++r) {
                    float scq = sScale[w * 16 + g4 * 4 + r];
                    acc[nt][r] *= scq;
                }
            }
            bf16x8 aP = *(const bf16x8*)&sP[(w * 16 + l16) * 40 + g4 * 8];
            #pragma unroll
            for (int nn = 0; nn < 2; ++nn) {
                bf16x8 bV = *(const bf16x8*)&sVT[(h * 32 + nn * 16 + l16) * 40 + g4 * 8];
                acc[2 * h + nn] = MFMA(aP, bV, acc[2 * h + nn], 0, 0, 0);
            }
        }
        __syncthreads();
    }
    __syncthreads();
    size_t mlbase = (((size_t)b * KS + chunk) * NH) * 128 * 2;
    for (int e = tid; e < NH * 128; e += 512) {
        ml[mlbase + e * 2 + 0] = sM[e];
        ml[mlbase + e * 2 + 1] = sL[e];
    }
    size_t abase = (((size_t)b * KS + chunk) * 128) * 128;
    #pragma unroll
    for (int n = 0; n < 8; ++n)
        #pragma unroll
        for (int r = 0; r < 4; ++r) {
            int q = w * 16 + g4 * 4 + r;
            int d = n * 16 + l16;
            accp[abase + (size_t)q * 128 + d] = f2b(acc[n][r]);
        }
}

// ---------------- fused: merge MAB0 partials -> O0 -> H -> Kh1b/Vh1Tb ----------------
__global__ __launch_bounds__(128)
void k_post0(const float* __restrict__ ml, const unsigned short* __restrict__ accp,
             const float* __restrict__ Qh0f,
             const float* __restrict__ Wo0, const float* __restrict__ bo0,
             const float* __restrict__ Wk1, const float* __restrict__ bk1,
             const float* __restrict__ Wv1, const float* __restrict__ bv1,
             unsigned short* __restrict__ Kh1b, unsigned short* __restrict__ Vh1Tb)
{
    int q = blockIdx.x, b = blockIdx.y, d = threadIdx.x, h = d >> 5;
    __shared__ float sx[128], sh2[128];
    float M = -1e30f;
    for (int c = 0; c < KS; ++c)
        M = fmaxf(M, ml[((((size_t)b * KS + c) * NH + h) * 128 + q) * 2]);
    float L = 0.f, A = 0.f;
    for (int c = 0; c < KS; ++c) {
        size_t base = ((((size_t)b * KS + c) * NH + h) * 128 + q) * 2;
        float sc = __expf(ml[base] - M);
        L += sc * ml[base + 1];
        A += sc * b2f(accp[(((size_t)b * KS + c) * 128 + q) * 128 + d]);
    }
    float o0 = Qh0f[q * 128 + d] + ((L > 0.f) ? A / L : 0.f);
    sx[d] = o0;
    __syncthreads();
    float acc = bo0[d];
    for (int i = 0; i < 128; ++i) acc += sx[i] * Wo0[i * 128 + d];
    float hv = o0 + fmaxf(acc, 0.f);
    sh2[d] = hv;
    __syncthreads();
    float ak = bk1[d], av = bv1[d];
    for (int i = 0; i < 128; ++i) {
        float x = sh2[i];
        ak += x * Wk1[i * 128 + d];
        av += x * Wv1[i * 128 + d];
    }
    Kh1b[((size_t)b * 128 + q) * 128 + d] = f2b(ak);
    Vh1Tb[((size_t)b * 128 + d) * 128 + q] = f2b(av);
}

// ---------------- MAB1 fused (MFMA, in-register softmax), 64 rows/block ----------------
__global__ __launch_bounds__(512, 6)
void k_mab1(float* __restrict__ Z, const unsigned short* __restrict__ Kh1b,
            const unsigned short* __restrict__ Vh1Tb,
            const unsigned short* __restrict__ WqT, const float* __restrict__ bq1,
            const unsigned short* __restrict__ WoT, const float* __restrict__ bo1,
            const int* __restrict__ nvalid)
{
    const int b = blockIdx.y;
    const int p0 = blockIdx.x * 64;
    const int nv = nvalid[b];
    if (p0 >= nv) return;
    const int tid = threadIdx.x, lane = tid & 63, w = tid >> 6;
    const int l16 = lane & 15, g4 = lane >> 4;
    const f32x4 fz = {0.f, 0.f, 0.f, 0.f};

    __shared__ unsigned short sQh[64 * 136];      // Qh1 [q][d], becomes O in-place
    __shared__ unsigned short sU[8 * 16 * 136];   // phase1: staged Z (first 64*136); phase2: per-wave P scratch

    // ---- stage Z tile -> bf16 LDS (rows >= nv are zero in Z, no guard needed)
    {
        int r = tid >> 3, c = (tid & 7) * 16;
        const float* zr = &Z[((size_t)b * LL + p0 + r) * LAT + c];
        #pragma unroll
        for (int half = 0; half < 2; ++half) {
            float4 f0 = *(const float4*)(zr + half * 8);
            float4 f1 = *(const float4*)(zr + half * 8 + 4);
            bf16x8 v;
            ((unsigned short*)&v)[0] = f2b(f0.x);
            ((unsigned short*)&v)[1] = f2b(f0.y);
            ((unsigned short*)&v)[2] = f2b(f0.z);
            ((unsigned short*)&v)[3] = f2b(f0.w);
            ((unsigned short*)&v)[4] = f2b(f1.x);
            ((unsigned short*)&v)[5] = f2b(f1.y);
            ((unsigned short*)&v)[6] = f2b(f1.z);
            ((unsigned short*)&v)[7] = f2b(f1.w);
            *(bf16x8*)&sU[r * 136 + c + half * 8] = v;
        }
    }
    __syncthreads();
    // ---- Qh1 = Z @ Wq1 + bq1 ; wave w -> col-tile w
    {
        f32x4 c4[4] = {fz, fz, fz, fz};
        #pragma unroll
        for (int ks = 0; ks < 4; ++ks) {
            bf16x8 bw = *(const bf16x8*)&WqT[(w * 16 + l16) * 128 + ks * 32 + g4 * 8];
            #pragma unroll
            for (int mt = 0; mt < 4; ++mt) {
                bf16x8 a = *(const bf16x8*)&sU[(mt * 16 + l16) * 136 + ks * 32 + g4 * 8];
                c4[mt] = MFMA(a, bw, c4[mt], 0, 0, 0);
            }
        }
        float bqv = bq1[w * 16 + l16];
        #pragma unroll
        for (int mt = 0; mt < 4; ++mt)
            #pragma unroll
            for (int r = 0; r < 4; ++r)
                sQh[(mt * 16 + g4 * 4 + r) * 136 + w * 16 + l16] = f2b(c4[mt][r] + bqv);
    }
    __syncthreads();   // after this, sU is repurposed as per-wave P scratch

    const int t = w >> 1;             // q-tile (16 rows)
    const int hbase = (w & 1) * 2;    // this wave's heads: hbase, hbase+1
    unsigned short* ps = &sU[w * 16 * 136];
    f32x4 oacc[2][2];                 // [hh][nn]

    #pragma unroll
    for (int hh = 0; hh < 2; ++hh) {
        const int h = hbase + hh;
        // swapped scores: lane holds S[key = mt*16+g4*4+r][q = t*16+l16]
        f32x4 s[8];
        bf16x8 bq8 = *(const bf16x8*)&sQh[(t * 16 + l16) * 136 + h * 32 + g4 * 8];
        #pragma unroll
        for (int mt = 0; mt < 8; ++mt) {
            bf16x8 ak = *(const bf16x8*)&Kh1b[((size_t)b * 128 + mt * 16 + l16) * 128 + h * 32 + g4 * 8];
            s[mt] = MFMA(ak, bq8, fz, 0, 0, 0);
        }
        // in-register softmax over all 128 keys for q = t*16+l16
        float mx = -1e30f;
        #pragma unroll
        for (int mt = 0; mt < 8; ++mt)
            #pragma unroll
            for (int r = 0; r < 4; ++r) mx = fmaxf(mx, s[mt][r]);
        mx = fmaxf(mx, __shfl_xor(mx, 16));
        mx = fmaxf(mx, __shfl_xor(mx, 32));
        float ls = 0.f;
        #pragma unroll
        for (int mt = 0; mt < 8; ++mt)
            #pragma unroll
            for (int r = 0; r < 4; ++r) {
                float p = __expf((s[mt][r] - mx) * RSQ);
                s[mt][r] = p;
                ls += p;
            }
        ls += __shfl_xor(ls, 16);
        ls += __shfl_xor(ls, 32);
        float inv = 1.f / ls;
        // write scaled P to per-wave scratch: [qlocal=l16][key]
        #pragma unroll
        for (int mt = 0; mt < 8; ++mt) {
            unsigned short p4[4];
            #pragma unroll
            for (int r = 0; r < 4; ++r) p4[r] = f2b(s[mt][r] * inv);
            *(uint2*)&ps[l16 * 136 + mt * 16 + g4 * 4] = *(const uint2*)p4;
        }
        // PV: A = P rows from scratch, B = V^T rows from global
        #pragma unroll
        for (int nn = 0; nn < 2; ++nn) {
            f32x4 o = fz;
            #pragma unroll
            for (int ks = 0; ks < 4; ++ks) {
                bf16x8 aP = *(const bf16x8*)&ps[l16 * 136 + ks * 32 + g4 * 8];
                bf16x8 bV = *(const bf16x8*)&Vh1Tb[((size_t)b * 128 + h * 32 + nn * 16 + l16) * 128 + ks * 32 + g4 * 8];
                o = MFMA(aP, bV, o, 0, 0, 0);
            }
            oacc[hh][nn] = o;
        }
    }
    // O = Qh + attn, in-place into sQh (wave-disjoint row x col slices)
    #pragma unroll
    for (int hh = 0; hh < 2; ++hh)
        #pragma unroll
        for (int nn = 0; nn < 2; ++nn) {
            int col = (hbase + hh) * 32 + nn * 16 + l16;
            #pragma unroll
            for (int r = 0; r < 4; ++r) {
                int row = t * 16 + g4 * 4 + r;
                float val = oacc[hh][nn][r] + b2f(sQh[row * 136 + col]);
                sQh[row * 136 + col] = f2b(val);
            }
        }
    __syncthreads();
    // out = Zold + O + relu(O @ Wo1 + bo1); wave w -> col-tile w
    {
        f32x4 c4[4] = {fz, fz, fz, fz};
        #pragma unroll
        for (int ks = 0; ks < 4; ++ks) {
            bf16x8 bw = *(const bf16x8*)&WoT[(w * 16 + l16) * 128 + ks * 32 + g4 * 8];
            #pragma unroll
            for (int mt = 0; mt < 4; ++mt) {
                bf16x8 a = *(const bf16x8*)&sQh[(mt * 16 + l16) * 136 + ks * 32 + g4 * 8];
                c4[mt] = MFMA(a, bw, c4[mt], 0, 0, 0);
            }
        }
        float bov = bo1[w * 16 + l16];
        #pragma unroll
        for (int mt = 0; mt < 4; ++mt)
            #pragma unroll
            for (int r = 0; r < 4; ++r) {
                int row = mt * 16 + g4 * 4 + r;
                int col = w * 16 + l16;
                if (p0 + row < nv) {
                    size_t zi = ((size_t)b * LL + p0 + row) * LAT + col;
                    Z[zi] = Z[zi] + b2f(sQh[row * 136 + col]) + fmaxf(c4[mt][r] + bov, 0.f);
                }
            }
    }
}

extern "C" void kernel_launch(void* const* d_in, const int* in_sizes, int n_in,
                              void* d_out, int out_size, void* d_ws, size_t ws_size,
                              hipStream_t stream)
{
    const float* time_x  = (const float*)d_in[0];
    const float* value_x = (const float*)d_in[1];
    const int*   mask_x  = (const int*)d_in[2];
    const float* Wi = (const float*)d_in[3];
    const float* bi = (const float*)d_in[4];
    const float* I  = (const float*)d_in[5];
    const float* Wq = (const float*)d_in[6];
    const float* bq = (const float*)d_in[7];
    const float* Wk = (const float*)d_in[8];
    const float* bk = (const float*)d_in[9];
    const float* Wv = (const float*)d_in[10];
    const float* bv = (const float*)d_in[11];
    const float* Wo = (const float*)d_in[12];
    const float* bo = (const float*)d_in[13];
    float* out = (float*)d_out;

    const size_t BL = (size_t)BB * LL;
    float* ws = (float*)d_ws;
    float* compT  = ws;                      ws += BL;
    float* compU  = ws;                      ws += BL;
    int*   compC  = (int*)ws;                ws += BL;
    int*   nvalid = (int*)ws;                ws += 64;
    float* Qh0f   = ws;                      ws += (size_t)NL * 16384;
    float* ml     = ws;                      ws += (size_t)BB * KS * NH * 128 * 2;
    unsigned short* accp  = (unsigned short*)ws;  ws += ((size_t)BB * KS * 128 * 128) / 2;
    unsigned short* Qh0b  = (unsigned short*)ws;  ws += (size_t)NL * 8192;
    unsigned short* WkT   = (unsigned short*)ws;  ws += (size_t)NL * 8192;
    unsigned short* WvT   = (unsigned short*)ws;  ws += (size_t)NL * 8192;
    unsigned short* WqT   = (unsigned short*)ws;  ws += (size_t)NL * 8192;
    unsigned short* WoT   = (unsigned short*)ws;  ws += (size_t)NL * 8192;
    unsigned short* Kh1b  = (unsigned short*)ws;  ws += ((size_t)BB * 16384) / 2;
    unsigned short* Vh1Tb = (unsigned short*)ws;  ws += ((size_t)BB * 16384) / 2;

    k_compact<<<BB, 256, 0, stream>>>(time_x, value_x, mask_x, compT, compU, compC, nvalid);
    k_init<<<dim3(LL / 8, BB), 256, 0, stream>>>(Wi, bi, compT, compU, compC, nvalid, out);
    k_prep<<<dim3(132, NL), 256, 0, stream>>>(I, Wq, bq, Wk, Wv, Wo,
                                              Qh0f, Qh0b, WkT, WvT, WqT, WoT);

    for (int l = 0; l < NL; ++l) {
        const float* Wo0 = Wo + (size_t)(l * 2 + 0) * 16384;
        const float* Wk1 = Wk + (size_t)(l * 2 + 1) * 16384;
        const float* Wv1 = Wv + (size_t)(l * 2 + 1) * 16384;
        const float* bk0 = bk + (l * 2 + 0) * 128;
        const float* bv0 = bv + (l * 2 + 0) * 128;
        const float* bo0 = bo + (l * 2 + 0) * 128;
        const float* bq1 = bq + (l * 2 + 1) * 128;
        const float* bk1 = bk + (l * 2 + 1) * 128;
        const float* bv1 = bv + (l * 2 + 1) * 128;
        const float* bo1 = bo + (l * 2 + 1) * 128;

        k_flash0<<<dim3(KS, BB), 512, 0, stream>>>(out, Qh0b + (size_t)l * 16384,
                                                   WkT + (size_t)l * 16384,
                                                   WvT + (size_t)l * 16384,
                                                   bk0, bv0, nvalid, ml, accp);
        k_post0<<<dim3(128, BB), 128, 0, stream>>>(ml, accp, Qh0f + (size_t)l * 16384,
                                                   Wo0, bo0, Wk1, bk1, Wv1, bv1, Kh1b, Vh1Tb);
        k_mab1<<<dim3(LL / 64, BB), 512, 0, stream>>>(out, Kh1b, Vh1Tb,
                                                      WqT + (size_t)l * 16384, bq1,
                                                      WoT + (size_t)l * 16384, bo1, nvalid);
    }
}